// Round 7
// baseline (218.479 us; speedup 1.0000x reference)
//
#include <hip/hip_runtime.h>
#include <math.h>

#define N_NODES 50000
#define N_EDGES 25000
#define MAX_ARITY 6
#define MAX_DEG 8
#define NFEAT 128
#define NHID 64
#define NEMB 128
#define NHEADS 4
#define BATCH 4096

// padded m-tile counts (16 rows per tile)
#define MT_N 3128   // ceil(50000/128)*8 -> rows padded to 50048

typedef __bf16 bf16x8 __attribute__((ext_vector_type(8)));
typedef __bf16 bf16x4 __attribute__((ext_vector_type(4)));
typedef float f32x4 __attribute__((ext_vector_type(4)));
typedef float f32x2 __attribute__((ext_vector_type(2)));

__device__ __forceinline__ float wave_sum(float v) {
#pragma unroll
    for (int off = 1; off < 64; off <<= 1) v += __shfl_xor(v, off);
    return v;
}
__device__ __forceinline__ float group32_sum(float v) {
#pragma unroll
    for (int off = 1; off < 32; off <<= 1) v += __shfl_xor(v, off);
    return v;
}
__device__ __forceinline__ float group16_sum(float v) {
#pragma unroll
    for (int off = 1; off < 16; off <<= 1) v += __shfl_xor(v, off);
    return v;
}
__device__ __forceinline__ float group8_sum(float v) {
#pragma unroll
    for (int off = 1; off < 8; off <<= 1) v += __shfl_xor(v, off);
    return v;
}
__device__ __forceinline__ float lrelu(float x) { return x >= 0.f ? x : 0.2f * x; }
__device__ __forceinline__ float eluf(float x) { return x > 0.f ? x : expm1f(x); }

// ---- fp8 e4m3 (OCP on gfx950) pack/unpack helpers ----
__device__ __forceinline__ int2 pack_fp8x8(const float* v) {
    int w0 = __builtin_amdgcn_cvt_pk_fp8_f32(v[0], v[1], 0, 0);
    w0 = __builtin_amdgcn_cvt_pk_fp8_f32(v[2], v[3], w0, 1);
    int w1 = __builtin_amdgcn_cvt_pk_fp8_f32(v[4], v[5], 0, 0);
    w1 = __builtin_amdgcn_cvt_pk_fp8_f32(v[6], v[7], w1, 1);
    int2 o;
    o.x = w0;
    o.y = w1;
    return o;
}
__device__ __forceinline__ void unpack_fp8x8(int2 w, float* v) {
    f32x2 a = __builtin_amdgcn_cvt_pk_f32_fp8(w.x, false);
    f32x2 b = __builtin_amdgcn_cvt_pk_f32_fp8(w.x, true);
    f32x2 c = __builtin_amdgcn_cvt_pk_f32_fp8(w.y, false);
    f32x2 d = __builtin_amdgcn_cvt_pk_f32_fp8(w.y, true);
    v[0] = a[0]; v[1] = a[1]; v[2] = b[0]; v[3] = b[1];
    v[4] = c[0]; v[5] = c[1]; v[6] = d[0]; v[7] = d[1];
}
__device__ __forceinline__ unsigned char fp8_of(float x) {
    return (unsigned char)(__builtin_amdgcn_cvt_pk_fp8_f32(x, x, 0, 0) & 0xff);
}

// ---------------------------------------------------------------------------
// PREP mega-kernel: bconv(B1n) + bconv(B2n) + wvec1 + wvec2 + c1
// (repack eliminated: mgemm1 now reads node_embs f32 directly)
// ---------------------------------------------------------------------------
#define PREP_BCONV1_BLKS 16
#define PREP_BCONV2_BLKS 16
#define PREP_WVEC1_BLKS 2
#define PREP_WVEC2_BLKS 1
#define PREP_C1_BLKS 6250       // N_EDGES/4
#define PREP_TOTAL_BLKS (PREP_BCONV1_BLKS + PREP_BCONV2_BLKS + \
                         PREP_WVEC1_BLKS + PREP_WVEC2_BLKS + PREP_C1_BLKS)

__global__ __launch_bounds__(256) void prep_kernel(
    const float* __restrict__ edge_embs, const float* __restrict__ Wn,
    const float* __restrict__ We, const float* __restrict__ a1, const float* __restrict__ Wn_o,
    const float* __restrict__ We_o, const float* __restrict__ a1_o, __bf16* __restrict__ B1n,
    __bf16* __restrict__ B2n, float* __restrict__ wc1, float* __restrict__ wc2,
    float* __restrict__ c1) {
    int blk = blockIdx.x;
    if (blk < PREP_BCONV1_BLKS) {
        // Wn (4,128,64) -> B1n frag order [kt][nt][lane][8], KT=4, NT=16
        int t = blk * 256 + threadIdx.x;
        int lane = t & 63;
        int nt = (t >> 6) & 15;
        int kt = t >> 10;
        int k0 = kt * 32 + (lane >> 4) * 8;
        int h = nt >> 2;
        int nl = (nt & 3) * 16 + (lane & 15);
        bf16x8 o;
#pragma unroll
        for (int j = 0; j < 8; ++j) o[j] = (__bf16)Wn[(h * NFEAT + k0 + j) * NHID + nl];
        reinterpret_cast<bf16x8*>(B1n)[t] = o;
        return;
    }
    blk -= PREP_BCONV1_BLKS;
    if (blk < PREP_BCONV2_BLKS) {
        // Wn_o (256,128) -> B2n frag order [kt][nt][lane][8], KT=8, NT=8
        int t = blk * 256 + threadIdx.x;
        int lane = t & 63;
        int nt = (t >> 6) & 7;
        int kt = t >> 9;
        int k0 = kt * 32 + (lane >> 4) * 8;
        int n = nt * 16 + (lane & 15);
        bf16x8 o;
#pragma unroll
        for (int j = 0; j < 8; ++j) o[j] = (__bf16)Wn_o[(size_t)(k0 + j) * 128 + n];
        reinterpret_cast<bf16x8*>(B2n)[t] = o;
        return;
    }
    blk -= PREP_BCONV2_BLKS;
    if (blk < PREP_WVEC1_BLKS) {
        int t = blk * 256 + threadIdx.x;
        int h = t >> 7, k = t & 127;
        float s = 0.f;
        for (int j = 0; j < 64; ++j) s += We[(h * NFEAT + k) * NHID + j] * a1[h * 128 + j];
        wc1[t] = s;
        return;
    }
    blk -= PREP_WVEC1_BLKS;
    if (blk < PREP_WVEC2_BLKS) {
        int t = threadIdx.x;
        float s = 0.f;
        for (int j = 0; j < 128; ++j) s += We_o[(size_t)t * 128 + j] * a1_o[j];
        wc2[t] = s;
        return;
    }
    blk -= PREP_WVEC2_BLKS;
    {
        int r = blk * 4 + (threadIdx.x >> 6);
        int lane = threadIdx.x & 63;
        if (r >= N_EDGES) return;
        float x0 = edge_embs[(size_t)r * 128 + lane];
        float x1 = edge_embs[(size_t)r * 128 + 64 + lane];
#pragma unroll
        for (int h = 0; h < 4; ++h) {
            float s = wave_sum(x0 * wc1[h * 128 + lane] + x1 * wc1[h * 128 + 64 + lane]);
            if (lane == 0) c1[r * 4 + h] = s;
        }
    }
}

// ---------------------------------------------------------------------------
// GEMM1: hn1(fp8) = node_embs(f32, read direct + inline bf16 cvt) @ B1n
// + fused dots d1 = hn1.a1[:,64:], g1v = hn1.a2[:,:64].  KT=4, BNF=4, MPW=2.
// ---------------------------------------------------------------------------
__global__ __launch_bounds__(256) void mgemm1_kernel(
    const float* __restrict__ Af32, const __bf16* __restrict__ B,
    unsigned char* __restrict__ C, const float* __restrict__ a1v,
    const float* __restrict__ a2v, float* __restrict__ d1, float* __restrict__ g1v) {
    const int w = threadIdx.x >> 6, l = threadIdx.x & 63;
    const int mtb = blockIdx.y * 8 + w * 2;
    const int nbf = blockIdx.x * 4;
    const int lr = l & 15, lk = (l >> 4) * 8;
    f32x4 acc[2][4];
#pragma unroll
    for (int i = 0; i < 2; ++i)
#pragma unroll
        for (int j = 0; j < 4; ++j) acc[i][j] = (f32x4){0.f, 0.f, 0.f, 0.f};
    const bf16x8* Bp = reinterpret_cast<const bf16x8*>(B) + l;
#pragma unroll
    for (int kt = 0; kt < 4; ++kt) {
        bf16x8 a[2];
#pragma unroll
        for (int mi = 0; mi < 2; ++mi) {
            int row = (mtb + mi) * 16 + lr;
            int ks = kt * 32 + lk;
            float v[8];
            if (row < N_NODES) {
                float4 p0 = *reinterpret_cast<const float4*>(Af32 + (size_t)row * 128 + ks);
                float4 p1 = *reinterpret_cast<const float4*>(Af32 + (size_t)row * 128 + ks + 4);
                v[0] = p0.x; v[1] = p0.y; v[2] = p0.z; v[3] = p0.w;
                v[4] = p1.x; v[5] = p1.y; v[6] = p1.z; v[7] = p1.w;
            } else {
#pragma unroll
                for (int j = 0; j < 8; ++j) v[j] = 0.f;
            }
#pragma unroll
            for (int j = 0; j < 8; ++j) a[mi][j] = (__bf16)v[j];
        }
#pragma unroll
        for (int nj = 0; nj < 4; ++nj) {
            bf16x8 b = Bp[((size_t)kt * 16 + nbf + nj) * 64];
#pragma unroll
            for (int mi = 0; mi < 2; ++mi)
                acc[mi][nj] = __builtin_amdgcn_mfma_f32_16x16x32_bf16(a[mi], b, acc[mi][nj], 0, 0, 0);
        }
    }
    const int rq = (l >> 4) * 4;
    const int cl = l & 15;
    const int h = nbf >> 2;
    float va[4], vb[4];
#pragma unroll
    for (int nj = 0; nj < 4; ++nj) {
        int col = ((nbf + nj) & 3) * 16 + cl;
        va[nj] = a1v[h * 128 + 64 + col];
        vb[nj] = a2v[h * 128 + col];
    }
#pragma unroll
    for (int mi = 0; mi < 2; ++mi) {
#pragma unroll
        for (int q = 0; q < 4; ++q) {
            int m = (mtb + mi) * 16 + rq + q;
            float pA = 0.f, pB = 0.f;
#pragma unroll
            for (int nj = 0; nj < 4; ++nj) {
                pA += acc[mi][nj][q] * va[nj];
                pB += acc[mi][nj][q] * vb[nj];
            }
            if (m < N_NODES) {
#pragma unroll
                for (int nj = 0; nj < 4; ++nj)
                    C[(size_t)m * 256 + (nbf + nj) * 16 + cl] = fp8_of(acc[mi][nj][q]);
            }
            pA = group16_sum(pA);
            pB = group16_sum(pB);
            if (cl == 0 && m < N_NODES) {
                d1[m * 4 + h] = pA;
                g1v[m * 4 + h] = pB;
            }
        }
    }
}

// ---------------------------------------------------------------------------
// Layer-1 EDGE attention: 2 edges/wave, 32 lanes/edge, lane owns 8 feats.
// feat (hn1) fp8; output eo1 fp8; gathers prefetched before score compute.
// ---------------------------------------------------------------------------
__global__ __launch_bounds__(256) void attn64e_kernel(
    const int* __restrict__ nbr, const unsigned char* __restrict__ feat,
    const float* __restrict__ sdot, const float* __restrict__ ndot,
    const float* __restrict__ a2v, const float* __restrict__ wc2,
    unsigned char* __restrict__ eo1, float* __restrict__ f1, float* __restrict__ c2, int rows) {
    const int lane = threadIdx.x & 63;
    const int half = lane >> 5, lp = lane & 31;
    const int r = (blockIdx.x * 4 + (threadIdx.x >> 6)) * 2 + half;
    if (r >= rows) return;
    const int h = lp >> 3;
    int id[MAX_ARITY];
    bool val[MAX_ARITY];
#pragma unroll
    for (int a = 0; a < MAX_ARITY; ++a) {
        int v = nbr[r * MAX_ARITY + a];
        val[a] = v > 0;
        id[a] = val[a] ? (v - 1) : 0;
    }
    int2 f8[MAX_ARITY];
    float nd[MAX_ARITY];
#pragma unroll
    for (int a = 0; a < MAX_ARITY; ++a) {
        f8[a] = *reinterpret_cast<const int2*>(feat + (size_t)id[a] * 256 + lp * 8);
        nd[a] = ndot[(size_t)id[a] * 4 + h];
    }
    const float c = sdot[r * 4 + h];
    float wgt[MAX_ARITY];
    float smax = -1e30f;
#pragma unroll
    for (int a = 0; a < MAX_ARITY; ++a) {
        float s = val[a] ? lrelu(c + nd[a]) : -3e30f;
        wgt[a] = s;
        if (val[a]) smax = fmaxf(smax, s);
    }
    float denom = 0.f;
#pragma unroll
    for (int a = 0; a < MAX_ARITY; ++a) {
        float ex = val[a] ? expf(wgt[a] - smax) : 0.f;
        wgt[a] = ex;
        denom += ex;
    }
    float inv = 1.f / denom;
    float acc[8] = {0.f, 0.f, 0.f, 0.f, 0.f, 0.f, 0.f, 0.f};
#pragma unroll
    for (int a = 0; a < MAX_ARITY; ++a) {
        float fv[8];
        unpack_fp8x8(f8[a], fv);
#pragma unroll
        for (int j = 0; j < 8; ++j) acc[j] = fmaf(wgt[a], fv[j], acc[j]);
    }
#pragma unroll
    for (int j = 0; j < 8; ++j) acc[j] *= inv;
    *reinterpret_cast<int2*>(eo1 + (size_t)r * 256 + lp * 8) = pack_fp8x8(acc);
    float p = 0.f;
#pragma unroll
    for (int j = 0; j < 8; ++j) p += acc[j] * a2v[h * 128 + 64 + (lp & 7) * 8 + j];
    p = group8_sum(p);
    if ((lp & 7) == 0) f1[r * 4 + h] = p;
    float p2 = 0.f;
#pragma unroll
    for (int j = 0; j < 8; ++j) p2 += eluf(acc[j]) * wc2[lp * 8 + j];
    p2 = group32_sum(p2);
    if (lp == 0) c2[r] = p2;
}

// ---------------------------------------------------------------------------
// FUSE2: layer-1 NODE attention + GEMM2 in one kernel.
// Block = 256 thr (4 waves) owns 64 node rows (4 m-tiles) and all 128 cols.
// Phase 1: each wave computes attention (gather eo1 fp8) for 16 nodes,
//          writing elu'd bf16 rows into LDS [64][260] (pad 4 -> 2-way-free).
// Phase 2: wave w runs MFMA for m-tile w from LDS; writes hn2 bf16 + d2,g2v.
// ---------------------------------------------------------------------------
#define LDSW 260

__global__ __launch_bounds__(256) void fuse2_kernel(
    const int* __restrict__ nbr, const unsigned char* __restrict__ feat,
    const float* __restrict__ sdot, const float* __restrict__ ndot,
    const __bf16* __restrict__ B, __bf16* __restrict__ hn2, const float* __restrict__ a1o,
    const float* __restrict__ a2o, float* __restrict__ d2, float* __restrict__ g2v) {
    __shared__ __bf16 Alds[64 * LDSW];
    const int w = threadIdx.x >> 6, lane = threadIdx.x & 63;
    const int half = lane >> 5, lp = lane & 31;
    const int h = lp >> 3;
    // ---- phase 1: attention for this block's 64 rows ----
#pragma unroll
    for (int p = 0; p < 8; ++p) {
        const int rl = w * 16 + p * 2 + half;
        const int r = blockIdx.x * 64 + rl;
        __bf16* dptr = &Alds[rl * LDSW + lp * 8];
        if (r >= N_NODES) {
            bf16x8 z;
#pragma unroll
            for (int j = 0; j < 8; ++j) z[j] = (__bf16)0.f;
            *reinterpret_cast<bf16x8*>(dptr) = z;
            continue;
        }
        int id[MAX_DEG];
        bool val[MAX_DEG];
#pragma unroll
        for (int a = 0; a < MAX_DEG; ++a) {
            int v = nbr[r * MAX_DEG + a];
            val[a] = v > 0;
            id[a] = val[a] ? (v - 1) : 0;
        }
        int2 f8[MAX_DEG];
        float nd[MAX_DEG];
#pragma unroll
        for (int a = 0; a < MAX_DEG; ++a) {
            f8[a] = *reinterpret_cast<const int2*>(feat + (size_t)id[a] * 256 + lp * 8);
            nd[a] = ndot[(size_t)id[a] * 4 + h];
        }
        const float c = sdot[r * 4 + h];
        float wgt[MAX_DEG];
        float smax = -1e30f;
#pragma unroll
        for (int a = 0; a < MAX_DEG; ++a) {
            float s = val[a] ? lrelu(c + nd[a]) : -3e30f;
            wgt[a] = s;
            if (val[a]) smax = fmaxf(smax, s);
        }
        float denom = 0.f;
#pragma unroll
        for (int a = 0; a < MAX_DEG; ++a) {
            float ex = val[a] ? expf(wgt[a] - smax) : 0.f;
            wgt[a] = ex;
            denom += ex;
        }
        float inv = 1.f / denom;
        float acc[8] = {0.f, 0.f, 0.f, 0.f, 0.f, 0.f, 0.f, 0.f};
#pragma unroll
        for (int a = 0; a < MAX_DEG; ++a) {
            float fv[8];
            unpack_fp8x8(f8[a], fv);
#pragma unroll
            for (int j = 0; j < 8; ++j) acc[j] = fmaf(wgt[a], fv[j], acc[j]);
        }
        bf16x8 o;
#pragma unroll
        for (int j = 0; j < 8; ++j) o[j] = (__bf16)eluf(acc[j] * inv);
        *reinterpret_cast<bf16x8*>(dptr) = o;
    }
    __syncthreads();
    // ---- phase 2: MFMA for m-tile w (local rows w*16..w*16+15) ----
    const int lr = lane & 15, lkq = lane >> 4;  // frag row, k-quarter
    f32x4 acc[8];
#pragma unroll
    for (int j = 0; j < 8; ++j) acc[j] = (f32x4){0.f, 0.f, 0.f, 0.f};
    const bf16x8* Bp = reinterpret_cast<const bf16x8*>(B) + lane;
#pragma unroll
    for (int kt = 0; kt < 8; ++kt) {
        bf16x8 a = *reinterpret_cast<const bf16x8*>(
            &Alds[(w * 16 + lr) * LDSW + kt * 32 + lkq * 8]);
#pragma unroll
        for (int nj = 0; nj < 8; ++nj) {
            bf16x8 b = Bp[((size_t)kt * 8 + nj) * 64];
            acc[nj] = __builtin_amdgcn_mfma_f32_16x16x32_bf16(a, b, acc[nj], 0, 0, 0);
        }
    }
    const int rq = lkq * 4;
    const int cl = lane & 15;
    const int gm0 = blockIdx.x * 64 + w * 16 + rq;
    float va[8], vb[8];
#pragma unroll
    for (int nj = 0; nj < 8; ++nj) {
        va[nj] = a1o[128 + nj * 16 + cl];
        vb[nj] = a2o[nj * 16 + cl];
    }
#pragma unroll
    for (int q = 0; q < 4; ++q) {
        int m = gm0 + q;
        float pA = 0.f, pB = 0.f;
#pragma unroll
        for (int nj = 0; nj < 8; ++nj) {
            pA += acc[nj][q] * va[nj];
            pB += acc[nj][q] * vb[nj];
        }
        if (m < N_NODES) {
#pragma unroll
            for (int nj = 0; nj < 8; ++nj)
                hn2[(size_t)m * 128 + nj * 16 + cl] = (__bf16)acc[nj][q];
        }
        pA = group16_sum(pA);
        pB = group16_sum(pB);
        if (cl == 0 && m < N_NODES) {
            d2[m] = pA;
            g2v[m] = pB;
        }
    }
}

// ---------------------------------------------------------------------------
// Layer-2 attention: 4 rows/wave; 16 lanes/row own 8 feats; prefetched (bf16).
// ---------------------------------------------------------------------------
template <int NNBR, bool DOT>
__global__ __launch_bounds__(256) void attn128_kernel(const int* __restrict__ nbr,
                                                      const __bf16* __restrict__ feat,
                                                      const float* __restrict__ sdot,
                                                      const float* __restrict__ ndot,
                                                      const float* __restrict__ fvec,
                                                      __bf16* __restrict__ outF,
                                                      float* __restrict__ outDot, int rows) {
    const int lane = threadIdx.x & 63;
    const int qt = lane >> 4, lq = lane & 15;
    const int r = (blockIdx.x * 4 + (threadIdx.x >> 6)) * 4 + qt;
    if (r >= rows) return;
    int id[NNBR];
    bool val[NNBR];
#pragma unroll
    for (int a = 0; a < NNBR; ++a) {
        int v = nbr[r * NNBR + a];
        val[a] = v > 0;
        id[a] = val[a] ? (v - 1) : 0;
    }
    bf16x8 f8[NNBR];
    float nd[NNBR];
#pragma unroll
    for (int a = 0; a < NNBR; ++a) {
        f8[a] = *reinterpret_cast<const bf16x8*>(feat + (size_t)id[a] * 128 + lq * 8);
        nd[a] = ndot[id[a]];
    }
    const float c = sdot[r];
    float wgt[NNBR];
    float smax = -1e30f;
#pragma unroll
    for (int a = 0; a < NNBR; ++a) {
        float s = val[a] ? lrelu(c + nd[a]) : -3e30f;
        wgt[a] = s;
        if (val[a]) smax = fmaxf(smax, s);
    }
    float denom = 0.f;
#pragma unroll
    for (int a = 0; a < NNBR; ++a) {
        float ex = val[a] ? expf(wgt[a] - smax) : 0.f;
        wgt[a] = ex;
        denom += ex;
    }
    float inv = 1.f / denom;
    float acc[8] = {0.f, 0.f, 0.f, 0.f, 0.f, 0.f, 0.f, 0.f};
#pragma unroll
    for (int a = 0; a < NNBR; ++a)
#pragma unroll
        for (int j = 0; j < 8; ++j) acc[j] = fmaf(wgt[a], (float)f8[a][j], acc[j]);
    bf16x8 o;
#pragma unroll
    for (int j = 0; j < 8; ++j) {
        acc[j] *= inv;
        o[j] = (__bf16)acc[j];
    }
    *reinterpret_cast<bf16x8*>(outF + (size_t)r * 128 + lq * 8) = o;
    if (DOT) {
        float p = 0.f;
#pragma unroll
        for (int j = 0; j < 8; ++j) p += acc[j] * fvec[128 + lq * 8 + j];
        p = group16_sum(p);
        if (lq == 0) outDot[r] = p;
    }
}

// ---------------------------------------------------------------------------
// Batch gather: 2 (b,slot) pairs per wave; 32 lanes own 4 feats each.
// ---------------------------------------------------------------------------
__global__ __launch_bounds__(256) void batch_kernel(const int* __restrict__ bi,
                                                    const __bf16* __restrict__ eo2,
                                                    const __bf16* __restrict__ no2,
                                                    float* __restrict__ out) {
    const int lane = threadIdx.x & 63;
    const int half = lane >> 5, lp = lane & 31;
    const int gw = (blockIdx.x * 4 + (threadIdx.x >> 6)) * 2 + half;
    if (gw >= BATCH * 7) return;
    int b = gw / 7, s = gw % 7;
    int last_nz = -1;
#pragma unroll
    for (int j = 0; j < 7; ++j)
        if (bi[b * 7 + j] != 0) last_nz = j;
    float4 v;
    if (s == 0) {
        int e = bi[b * 7] - 1;
        bf16x4 t = *reinterpret_cast<const bf16x4*>(eo2 + (size_t)e * 128 + lp * 4);
        v = make_float4(eluf((float)t[0]), eluf((float)t[1]), eluf((float)t[2]),
                        eluf((float)t[3]));
    } else if (s <= last_nz) {
        int nid = bi[b * 7 + s] - 1;
        if (nid < 0) nid += N_NODES;
        bf16x4 t = *reinterpret_cast<const bf16x4*>(no2 + (size_t)nid * 128 + lp * 4);
        v = make_float4(eluf((float)t[0]), eluf((float)t[1]), eluf((float)t[2]),
                        eluf((float)t[3]));
    } else {
        v = make_float4(1.f, 1.f, 1.f, 1.f);
    }
    *reinterpret_cast<float4*>(out + (size_t)b * 896 + s * 128 + lp * 4) = v;
}

// ---------------------------------------------------------------------------
extern "C" void kernel_launch(void* const* d_in, const int* in_sizes, int n_in,
                              void* d_out, int out_size, void* d_ws, size_t ws_size,
                              hipStream_t stream) {
    const int* batch_inputs = (const int*)d_in[0];
    const int* edge_list = (const int*)d_in[1];
    const int* node_list = (const int*)d_in[2];
    const float* node_embs = (const float*)d_in[3];
    const float* edge_embs = (const float*)d_in[4];
    const float* Wn = (const float*)d_in[5];
    const float* We = (const float*)d_in[6];
    const float* a1 = (const float*)d_in[7];
    const float* a2 = (const float*)d_in[8];
    const float* Wn_o = (const float*)d_in[9];
    const float* We_o = (const float*)d_in[10];
    const float* a1_o = (const float*)d_in[11];
    const float* a2_o = (const float*)d_in[12];
    float* out = (float*)d_out;
    char* ws = (char*)d_ws;

    // ---- workspace layout (bytes) ----
    __bf16* B1n = (__bf16*)(ws);                      // 65,536
    __bf16* B2n = (__bf16*)(ws + 65536);              // 65,536
    float* wc1 = (float*)(ws + 131072);               // 2,048
    float* wc2 = (float*)(ws + 133120);               // 1,024
    float* c1 = (float*)(ws + 134144);                // 400,000
    float* d1 = (float*)(ws + 534144);                // 800,000
    float* g1v = (float*)(ws + 1334144);              // 800,000
    float* f1 = (float*)(ws + 2134144);               // 400,000
    float* c2 = (float*)(ws + 2534144);               // 100,000
    float* d2 = (float*)(ws + 2634144);               // 200,000
    float* g2v = (float*)(ws + 2834144);              // 200,000
    float* f2 = (float*)(ws + 3034144);               // 100,000
    unsigned char* hn1 = (unsigned char*)(ws + 3134144);  // 12,800,000 (50000x256 fp8)
    __bf16* hn2 = (__bf16*)(ws + 15934144);           // 12,800,000 (50000x128 bf16)
    unsigned char* eo1 = (unsigned char*)(ws + 28734144); // 6,400,000 (25000x256 fp8)
    __bf16* eo2 = (__bf16*)(ws + 35134144);           // 6,400,000
    __bf16* no2 = (__bf16*)(ws + 41534144);           // 12,800,000 -> ends 54,334,144

    // 1) merged prep (weight conversions + he-elimination dots)
    prep_kernel<<<PREP_TOTAL_BLKS, 256, 0, stream>>>(edge_embs, Wn, We, a1, Wn_o, We_o, a1_o,
                                                     B1n, B2n, wc1, wc2, c1);

    // 2) G1n: hn1(fp8) = node_embs(f32, direct) @ Wn  (+ d1, g1v)
    {
        dim3 g(4, MT_N / 8);
        mgemm1_kernel<<<g, 256, 0, stream>>>(node_embs, B1n, hn1, a1, a2, d1, g1v);
    }
    // 3) layer-1 edge attention -> eo1(fp8), f1, c2
    attn64e_kernel<<<(N_EDGES / 2 + 3) / 4, 256, 0, stream>>>(edge_list, hn1, c1, d1, a2, wc2,
                                                              eo1, f1, c2, N_EDGES);
    // 4) FUSE2: node attention (gather eo1) + GEMM2 -> hn2, d2, g2v
    fuse2_kernel<<<MT_N / 4, 256, 0, stream>>>(node_list, eo1, g1v, f1, B2n, hn2, a1_o, a2_o,
                                               d2, g2v);
    // 5) layer-2 edge attention -> eo2(bf16), f2
    attn128_kernel<MAX_ARITY, true><<<(N_EDGES / 4 + 3) / 4, 256, 0, stream>>>(
        edge_list, hn2, c2, d2, a2_o, eo2, f2, N_EDGES);
    // 6) layer-2 node attention -> no2(bf16)
    attn128_kernel<MAX_DEG, false><<<(N_NODES / 4 + 3) / 4, 256, 0, stream>>>(
        node_list, eo2, g2v, f2, nullptr, no2, nullptr, N_NODES);
    // 7) batch gather
    batch_kernel<<<(BATCH * 7 / 2 + 3) / 4, 256, 0, stream>>>(batch_inputs, eo2, no2, out);
}

// Round 8
// 209.062 us; speedup vs baseline: 1.0450x; 1.0450x over previous
//
#include <hip/hip_runtime.h>
#include <math.h>

#define N_NODES 50000
#define N_EDGES 25000
#define MAX_ARITY 6
#define MAX_DEG 8
#define NFEAT 128
#define NHID 64
#define NEMB 128
#define NHEADS 4
#define BATCH 4096

// padded m-tile counts (16 rows per tile)
#define MT_N 3128   // ceil(50000/128)*8 -> rows padded to 50048

typedef __bf16 bf16x8 __attribute__((ext_vector_type(8)));
typedef __bf16 bf16x4 __attribute__((ext_vector_type(4)));
typedef float f32x4 __attribute__((ext_vector_type(4)));
typedef float f32x2 __attribute__((ext_vector_type(2)));

__device__ __forceinline__ float wave_sum(float v) {
#pragma unroll
    for (int off = 1; off < 64; off <<= 1) v += __shfl_xor(v, off);
    return v;
}
__device__ __forceinline__ float group32_sum(float v) {
#pragma unroll
    for (int off = 1; off < 32; off <<= 1) v += __shfl_xor(v, off);
    return v;
}
__device__ __forceinline__ float group16_sum(float v) {
#pragma unroll
    for (int off = 1; off < 16; off <<= 1) v += __shfl_xor(v, off);
    return v;
}
__device__ __forceinline__ float group8_sum(float v) {
#pragma unroll
    for (int off = 1; off < 8; off <<= 1) v += __shfl_xor(v, off);
    return v;
}
__device__ __forceinline__ float lrelu(float x) { return x >= 0.f ? x : 0.2f * x; }
__device__ __forceinline__ float eluf(float x) { return x > 0.f ? x : expm1f(x); }

// ---- fp8 e4m3 (OCP on gfx950) pack/unpack helpers ----
__device__ __forceinline__ int2 pack_fp8x8(const float* v) {
    int w0 = __builtin_amdgcn_cvt_pk_fp8_f32(v[0], v[1], 0, 0);
    w0 = __builtin_amdgcn_cvt_pk_fp8_f32(v[2], v[3], w0, 1);
    int w1 = __builtin_amdgcn_cvt_pk_fp8_f32(v[4], v[5], 0, 0);
    w1 = __builtin_amdgcn_cvt_pk_fp8_f32(v[6], v[7], w1, 1);
    int2 o;
    o.x = w0;
    o.y = w1;
    return o;
}
__device__ __forceinline__ void unpack_fp8x8(int2 w, float* v) {
    f32x2 a = __builtin_amdgcn_cvt_pk_f32_fp8(w.x, false);
    f32x2 b = __builtin_amdgcn_cvt_pk_f32_fp8(w.x, true);
    f32x2 c = __builtin_amdgcn_cvt_pk_f32_fp8(w.y, false);
    f32x2 d = __builtin_amdgcn_cvt_pk_f32_fp8(w.y, true);
    v[0] = a[0]; v[1] = a[1]; v[2] = b[0]; v[3] = b[1];
    v[4] = c[0]; v[5] = c[1]; v[6] = d[0]; v[7] = d[1];
}
__device__ __forceinline__ unsigned char fp8_of(float x) {
    return (unsigned char)(__builtin_amdgcn_cvt_pk_fp8_f32(x, x, 0, 0) & 0xff);
}

// ---------------------------------------------------------------------------
// PREP mega-kernel: bconv(B1n) + bconv(B2n) + wvec1 + wvec2 + c1
// ---------------------------------------------------------------------------
#define PREP_BCONV1_BLKS 16
#define PREP_BCONV2_BLKS 16
#define PREP_WVEC1_BLKS 2
#define PREP_WVEC2_BLKS 1
#define PREP_C1_BLKS 6250       // N_EDGES/4
#define PREP_TOTAL_BLKS (PREP_BCONV1_BLKS + PREP_BCONV2_BLKS + \
                         PREP_WVEC1_BLKS + PREP_WVEC2_BLKS + PREP_C1_BLKS)

__global__ __launch_bounds__(256) void prep_kernel(
    const float* __restrict__ edge_embs, const float* __restrict__ Wn,
    const float* __restrict__ We, const float* __restrict__ a1, const float* __restrict__ Wn_o,
    const float* __restrict__ We_o, const float* __restrict__ a1_o, __bf16* __restrict__ B1n,
    __bf16* __restrict__ B2n, float* __restrict__ wc1, float* __restrict__ wc2,
    float* __restrict__ c1) {
    int blk = blockIdx.x;
    if (blk < PREP_BCONV1_BLKS) {
        int t = blk * 256 + threadIdx.x;
        int lane = t & 63;
        int nt = (t >> 6) & 15;
        int kt = t >> 10;
        int k0 = kt * 32 + (lane >> 4) * 8;
        int h = nt >> 2;
        int nl = (nt & 3) * 16 + (lane & 15);
        bf16x8 o;
#pragma unroll
        for (int j = 0; j < 8; ++j) o[j] = (__bf16)Wn[(h * NFEAT + k0 + j) * NHID + nl];
        reinterpret_cast<bf16x8*>(B1n)[t] = o;
        return;
    }
    blk -= PREP_BCONV1_BLKS;
    if (blk < PREP_BCONV2_BLKS) {
        int t = blk * 256 + threadIdx.x;
        int lane = t & 63;
        int nt = (t >> 6) & 7;
        int kt = t >> 9;
        int k0 = kt * 32 + (lane >> 4) * 8;
        int n = nt * 16 + (lane & 15);
        bf16x8 o;
#pragma unroll
        for (int j = 0; j < 8; ++j) o[j] = (__bf16)Wn_o[(size_t)(k0 + j) * 128 + n];
        reinterpret_cast<bf16x8*>(B2n)[t] = o;
        return;
    }
    blk -= PREP_BCONV2_BLKS;
    if (blk < PREP_WVEC1_BLKS) {
        int t = blk * 256 + threadIdx.x;
        int h = t >> 7, k = t & 127;
        float s = 0.f;
        for (int j = 0; j < 64; ++j) s += We[(h * NFEAT + k) * NHID + j] * a1[h * 128 + j];
        wc1[t] = s;
        return;
    }
    blk -= PREP_WVEC1_BLKS;
    if (blk < PREP_WVEC2_BLKS) {
        int t = threadIdx.x;
        float s = 0.f;
        for (int j = 0; j < 128; ++j) s += We_o[(size_t)t * 128 + j] * a1_o[j];
        wc2[t] = s;
        return;
    }
    blk -= PREP_WVEC2_BLKS;
    {
        int r = blk * 4 + (threadIdx.x >> 6);
        int lane = threadIdx.x & 63;
        if (r >= N_EDGES) return;
        float x0 = edge_embs[(size_t)r * 128 + lane];
        float x1 = edge_embs[(size_t)r * 128 + 64 + lane];
#pragma unroll
        for (int h = 0; h < 4; ++h) {
            float s = wave_sum(x0 * wc1[h * 128 + lane] + x1 * wc1[h * 128 + 64 + lane]);
            if (lane == 0) c1[r * 4 + h] = s;
        }
    }
}

// ---------------------------------------------------------------------------
// GEMM1: hn1(fp8) = node_embs(f32, read direct + inline bf16 cvt) @ B1n
// + fused dots d1 = hn1.a1[:,64:], g1v = hn1.a2[:,:64].  KT=4, BNF=4, MPW=2.
// ---------------------------------------------------------------------------
__global__ __launch_bounds__(256) void mgemm1_kernel(
    const float* __restrict__ Af32, const __bf16* __restrict__ B,
    unsigned char* __restrict__ C, const float* __restrict__ a1v,
    const float* __restrict__ a2v, float* __restrict__ d1, float* __restrict__ g1v) {
    const int w = threadIdx.x >> 6, l = threadIdx.x & 63;
    const int mtb = blockIdx.y * 8 + w * 2;
    const int nbf = blockIdx.x * 4;
    const int lr = l & 15, lk = (l >> 4) * 8;
    f32x4 acc[2][4];
#pragma unroll
    for (int i = 0; i < 2; ++i)
#pragma unroll
        for (int j = 0; j < 4; ++j) acc[i][j] = (f32x4){0.f, 0.f, 0.f, 0.f};
    const bf16x8* Bp = reinterpret_cast<const bf16x8*>(B) + l;
#pragma unroll
    for (int kt = 0; kt < 4; ++kt) {
        bf16x8 a[2];
#pragma unroll
        for (int mi = 0; mi < 2; ++mi) {
            int row = (mtb + mi) * 16 + lr;
            int ks = kt * 32 + lk;
            float v[8];
            if (row < N_NODES) {
                float4 p0 = *reinterpret_cast<const float4*>(Af32 + (size_t)row * 128 + ks);
                float4 p1 = *reinterpret_cast<const float4*>(Af32 + (size_t)row * 128 + ks + 4);
                v[0] = p0.x; v[1] = p0.y; v[2] = p0.z; v[3] = p0.w;
                v[4] = p1.x; v[5] = p1.y; v[6] = p1.z; v[7] = p1.w;
            } else {
#pragma unroll
                for (int j = 0; j < 8; ++j) v[j] = 0.f;
            }
#pragma unroll
            for (int j = 0; j < 8; ++j) a[mi][j] = (__bf16)v[j];
        }
#pragma unroll
        for (int nj = 0; nj < 4; ++nj) {
            bf16x8 b = Bp[((size_t)kt * 16 + nbf + nj) * 64];
#pragma unroll
            for (int mi = 0; mi < 2; ++mi)
                acc[mi][nj] = __builtin_amdgcn_mfma_f32_16x16x32_bf16(a[mi], b, acc[mi][nj], 0, 0, 0);
        }
    }
    const int rq = (l >> 4) * 4;
    const int cl = l & 15;
    const int h = nbf >> 2;
    float va[4], vb[4];
#pragma unroll
    for (int nj = 0; nj < 4; ++nj) {
        int col = ((nbf + nj) & 3) * 16 + cl;
        va[nj] = a1v[h * 128 + 64 + col];
        vb[nj] = a2v[h * 128 + col];
    }
#pragma unroll
    for (int mi = 0; mi < 2; ++mi) {
#pragma unroll
        for (int q = 0; q < 4; ++q) {
            int m = (mtb + mi) * 16 + rq + q;
            float pA = 0.f, pB = 0.f;
#pragma unroll
            for (int nj = 0; nj < 4; ++nj) {
                pA += acc[mi][nj][q] * va[nj];
                pB += acc[mi][nj][q] * vb[nj];
            }
            if (m < N_NODES) {
#pragma unroll
                for (int nj = 0; nj < 4; ++nj)
                    C[(size_t)m * 256 + (nbf + nj) * 16 + cl] = fp8_of(acc[mi][nj][q]);
            }
            pA = group16_sum(pA);
            pB = group16_sum(pB);
            if (cl == 0 && m < N_NODES) {
                d1[m * 4 + h] = pA;
                g1v[m * 4 + h] = pB;
            }
        }
    }
}

// ---------------------------------------------------------------------------
// GEMM2: hn2(bf16) = A2n(frags) @ B2n + fused dots d2, g2v. KT=8, BNF=8, MPW=1.
// ---------------------------------------------------------------------------
__global__ __launch_bounds__(256) void mgemm2_kernel(
    const __bf16* __restrict__ A, const __bf16* __restrict__ B, __bf16* __restrict__ C,
    const float* __restrict__ a1o, const float* __restrict__ a2o, float* __restrict__ d2,
    float* __restrict__ g2v) {
    const int w = threadIdx.x >> 6, l = threadIdx.x & 63;
    const int mtb = blockIdx.y * 4 + w;
    f32x4 acc[8];
#pragma unroll
    for (int j = 0; j < 8; ++j) acc[j] = (f32x4){0.f, 0.f, 0.f, 0.f};
    const bf16x8* Ap = reinterpret_cast<const bf16x8*>(A) + (size_t)mtb * 8 * 64 + l;
    const bf16x8* Bp = reinterpret_cast<const bf16x8*>(B) + l;
#pragma unroll
    for (int kt = 0; kt < 8; ++kt) {
        bf16x8 a = Ap[(size_t)kt * 64];
#pragma unroll
        for (int nj = 0; nj < 8; ++nj) {
            bf16x8 b = Bp[((size_t)kt * 8 + nj) * 64];
            acc[nj] = __builtin_amdgcn_mfma_f32_16x16x32_bf16(a, b, acc[nj], 0, 0, 0);
        }
    }
    const int rq = (l >> 4) * 4;
    const int cl = l & 15;
    float va[8], vb[8];
#pragma unroll
    for (int nj = 0; nj < 8; ++nj) {
        va[nj] = a1o[128 + nj * 16 + cl];
        vb[nj] = a2o[nj * 16 + cl];
    }
#pragma unroll
    for (int q = 0; q < 4; ++q) {
        int m = mtb * 16 + rq + q;
        float pA = 0.f, pB = 0.f;
#pragma unroll
        for (int nj = 0; nj < 8; ++nj) {
            pA += acc[nj][q] * va[nj];
            pB += acc[nj][q] * vb[nj];
        }
        if (m < N_NODES) {
#pragma unroll
            for (int nj = 0; nj < 8; ++nj)
                C[(size_t)m * 128 + nj * 16 + cl] = (__bf16)acc[nj][q];
        }
        pA = group16_sum(pA);
        pB = group16_sum(pB);
        if (cl == 0 && m < N_NODES) {
            d2[m] = pA;
            g2v[m] = pB;
        }
    }
}

// ---------------------------------------------------------------------------
// Layer-1 EDGE attention: 2 edges/wave, 32 lanes/edge, lane owns 8 feats.
// feat (hn1) fp8; output eo1 fp8; gathers prefetched before score compute.
// ---------------------------------------------------------------------------
__global__ __launch_bounds__(256) void attn64e_kernel(
    const int* __restrict__ nbr, const unsigned char* __restrict__ feat,
    const float* __restrict__ sdot, const float* __restrict__ ndot,
    const float* __restrict__ a2v, const float* __restrict__ wc2,
    unsigned char* __restrict__ eo1, float* __restrict__ f1, float* __restrict__ c2, int rows) {
    const int lane = threadIdx.x & 63;
    const int half = lane >> 5, lp = lane & 31;
    const int r = (blockIdx.x * 4 + (threadIdx.x >> 6)) * 2 + half;
    if (r >= rows) return;
    const int h = lp >> 3;
    int id[MAX_ARITY];
    bool val[MAX_ARITY];
#pragma unroll
    for (int a = 0; a < MAX_ARITY; ++a) {
        int v = nbr[r * MAX_ARITY + a];
        val[a] = v > 0;
        id[a] = val[a] ? (v - 1) : 0;
    }
    int2 f8[MAX_ARITY];
    float nd[MAX_ARITY];
#pragma unroll
    for (int a = 0; a < MAX_ARITY; ++a) {
        f8[a] = *reinterpret_cast<const int2*>(feat + (size_t)id[a] * 256 + lp * 8);
        nd[a] = ndot[(size_t)id[a] * 4 + h];
    }
    const float c = sdot[r * 4 + h];
    float wgt[MAX_ARITY];
    float smax = -1e30f;
#pragma unroll
    for (int a = 0; a < MAX_ARITY; ++a) {
        float s = val[a] ? lrelu(c + nd[a]) : -3e30f;
        wgt[a] = s;
        if (val[a]) smax = fmaxf(smax, s);
    }
    float denom = 0.f;
#pragma unroll
    for (int a = 0; a < MAX_ARITY; ++a) {
        float ex = val[a] ? expf(wgt[a] - smax) : 0.f;
        wgt[a] = ex;
        denom += ex;
    }
    float inv = 1.f / denom;
    float acc[8] = {0.f, 0.f, 0.f, 0.f, 0.f, 0.f, 0.f, 0.f};
#pragma unroll
    for (int a = 0; a < MAX_ARITY; ++a) {
        float fv[8];
        unpack_fp8x8(f8[a], fv);
#pragma unroll
        for (int j = 0; j < 8; ++j) acc[j] = fmaf(wgt[a], fv[j], acc[j]);
    }
#pragma unroll
    for (int j = 0; j < 8; ++j) acc[j] *= inv;
    *reinterpret_cast<int2*>(eo1 + (size_t)r * 256 + lp * 8) = pack_fp8x8(acc);
    float p = 0.f;
#pragma unroll
    for (int j = 0; j < 8; ++j) p += acc[j] * a2v[h * 128 + 64 + (lp & 7) * 8 + j];
    p = group8_sum(p);
    if ((lp & 7) == 0) f1[r * 4 + h] = p;
    float p2 = 0.f;
#pragma unroll
    for (int j = 0; j < 8; ++j) p2 += eluf(acc[j]) * wc2[lp * 8 + j];
    p2 = group32_sum(p2);
    if (lp == 0) c2[r] = p2;
}

// ---------------------------------------------------------------------------
// Layer-1 NODE attention: 2 nodes/wave; feat (eo1) fp8; writes elu(out)
// directly as bf16 A-fragments for GEMM2 (KT=8). (high-occupancy standalone
// version — fusing this behind a barrier with GEMM2 regressed in R7)
// ---------------------------------------------------------------------------
__global__ __launch_bounds__(256) void attn64n_kernel(const int* __restrict__ nbr,
                                                      const unsigned char* __restrict__ feat,
                                                      const float* __restrict__ sdot,
                                                      const float* __restrict__ ndot,
                                                      __bf16* __restrict__ Afrag, int rows,
                                                      int rowsPad) {
    const int lane = threadIdx.x & 63;
    const int half = lane >> 5, lp = lane & 31;
    const int r = (blockIdx.x * 4 + (threadIdx.x >> 6)) * 2 + half;
    if (r >= rowsPad) return;
    const int rr = r & 15, mt = r >> 4;
    const int kt = lp >> 2, g = lp & 3;
    __bf16* dptr = Afrag + ((((size_t)mt * 8 + kt) * 64 + g * 16 + rr) << 3);
    if (r >= rows) {
        bf16x8 z;
#pragma unroll
        for (int j = 0; j < 8; ++j) z[j] = (__bf16)0.f;
        *reinterpret_cast<bf16x8*>(dptr) = z;
        return;
    }
    const int h = lp >> 3;
    int id[MAX_DEG];
    bool val[MAX_DEG];
#pragma unroll
    for (int a = 0; a < MAX_DEG; ++a) {
        int v = nbr[r * MAX_DEG + a];
        val[a] = v > 0;
        id[a] = val[a] ? (v - 1) : 0;
    }
    int2 f8[MAX_DEG];
    float nd[MAX_DEG];
#pragma unroll
    for (int a = 0; a < MAX_DEG; ++a) {
        f8[a] = *reinterpret_cast<const int2*>(feat + (size_t)id[a] * 256 + lp * 8);
        nd[a] = ndot[(size_t)id[a] * 4 + h];
    }
    const float c = sdot[r * 4 + h];
    float wgt[MAX_DEG];
    float smax = -1e30f;
#pragma unroll
    for (int a = 0; a < MAX_DEG; ++a) {
        float s = val[a] ? lrelu(c + nd[a]) : -3e30f;
        wgt[a] = s;
        if (val[a]) smax = fmaxf(smax, s);
    }
    float denom = 0.f;
#pragma unroll
    for (int a = 0; a < MAX_DEG; ++a) {
        float ex = val[a] ? expf(wgt[a] - smax) : 0.f;
        wgt[a] = ex;
        denom += ex;
    }
    float inv = 1.f / denom;
    float acc[8] = {0.f, 0.f, 0.f, 0.f, 0.f, 0.f, 0.f, 0.f};
#pragma unroll
    for (int a = 0; a < MAX_DEG; ++a) {
        float fv[8];
        unpack_fp8x8(f8[a], fv);
#pragma unroll
        for (int j = 0; j < 8; ++j) acc[j] = fmaf(wgt[a], fv[j], acc[j]);
    }
    bf16x8 o;
#pragma unroll
    for (int j = 0; j < 8; ++j) o[j] = (__bf16)eluf(acc[j] * inv);
    *reinterpret_cast<bf16x8*>(dptr) = o;
}

// ---------------------------------------------------------------------------
// Layer-2 EDGE attention: 4 rows/wave; 16 lanes/row own 8 feats (bf16).
// ---------------------------------------------------------------------------
__global__ __launch_bounds__(256) void attn128e_kernel(
    const int* __restrict__ nbr, const __bf16* __restrict__ feat,
    const float* __restrict__ sdot, const float* __restrict__ ndot,
    const float* __restrict__ fvec, __bf16* __restrict__ outF, float* __restrict__ outDot,
    int rows) {
    const int lane = threadIdx.x & 63;
    const int qt = lane >> 4, lq = lane & 15;
    const int r = (blockIdx.x * 4 + (threadIdx.x >> 6)) * 4 + qt;
    if (r >= rows) return;
    int id[MAX_ARITY];
    bool val[MAX_ARITY];
#pragma unroll
    for (int a = 0; a < MAX_ARITY; ++a) {
        int v = nbr[r * MAX_ARITY + a];
        val[a] = v > 0;
        id[a] = val[a] ? (v - 1) : 0;
    }
    bf16x8 f8[MAX_ARITY];
    float nd[MAX_ARITY];
#pragma unroll
    for (int a = 0; a < MAX_ARITY; ++a) {
        f8[a] = *reinterpret_cast<const bf16x8*>(feat + (size_t)id[a] * 128 + lq * 8);
        nd[a] = ndot[id[a]];
    }
    const float c = sdot[r];
    float wgt[MAX_ARITY];
    float smax = -1e30f;
#pragma unroll
    for (int a = 0; a < MAX_ARITY; ++a) {
        float s = val[a] ? lrelu(c + nd[a]) : -3e30f;
        wgt[a] = s;
        if (val[a]) smax = fmaxf(smax, s);
    }
    float denom = 0.f;
#pragma unroll
    for (int a = 0; a < MAX_ARITY; ++a) {
        float ex = val[a] ? expf(wgt[a] - smax) : 0.f;
        wgt[a] = ex;
        denom += ex;
    }
    float inv = 1.f / denom;
    float acc[8] = {0.f, 0.f, 0.f, 0.f, 0.f, 0.f, 0.f, 0.f};
#pragma unroll
    for (int a = 0; a < MAX_ARITY; ++a)
#pragma unroll
        for (int j = 0; j < 8; ++j) acc[j] = fmaf(wgt[a], (float)f8[a][j], acc[j]);
    bf16x8 o;
#pragma unroll
    for (int j = 0; j < 8; ++j) {
        acc[j] *= inv;
        o[j] = (__bf16)acc[j];
    }
    *reinterpret_cast<bf16x8*>(outF + (size_t)r * 128 + lq * 8) = o;
    float p = 0.f;
#pragma unroll
    for (int j = 0; j < 8; ++j) p += acc[j] * fvec[128 + lq * 8 + j];
    p = group16_sum(p);
    if (lq == 0) outDot[r] = p;
}

// ---------------------------------------------------------------------------
// BATCH2: fused layer-2 NODE attention + batch gather.
// 2 (b,slot) pairs per wave; 32 lanes/pair own 4 feats each.
// slot 0: elu(eo2[edge]); slot 1..last_nz: compute node attention for that
// node on the fly from eo2/g2v/f2 (no no2 table, ~51% fewer node-attn rows).
// ---------------------------------------------------------------------------
__global__ __launch_bounds__(256) void batch2_kernel(
    const int* __restrict__ bi, const int* __restrict__ node_list,
    const __bf16* __restrict__ eo2, const float* __restrict__ g2v,
    const float* __restrict__ f2, float* __restrict__ out) {
    const int lane = threadIdx.x & 63;
    const int half = lane >> 5, lp = lane & 31;
    const int gw = (blockIdx.x * 4 + (threadIdx.x >> 6)) * 2 + half;
    if (gw >= BATCH * 7) return;
    const int b = gw / 7, s = gw % 7;
    int last_nz = -1;
#pragma unroll
    for (int j = 0; j < 7; ++j)
        if (bi[b * 7 + j] != 0) last_nz = j;
    float4 v;
    if (s == 0) {
        int e = bi[b * 7] - 1;
        bf16x4 t = *reinterpret_cast<const bf16x4*>(eo2 + (size_t)e * 128 + lp * 4);
        v = make_float4(eluf((float)t[0]), eluf((float)t[1]), eluf((float)t[2]),
                        eluf((float)t[3]));
    } else if (s <= last_nz) {
        int nid = bi[b * 7 + s] - 1;   // bi>0 here, so nid >= 0
        int id[MAX_DEG];
        bool val[MAX_DEG];
#pragma unroll
        for (int a = 0; a < MAX_DEG; ++a) {
            int e = node_list[nid * MAX_DEG + a];
            val[a] = e > 0;
            id[a] = val[a] ? (e - 1) : 0;
        }
        bf16x4 f8[MAX_DEG];
        float nd[MAX_DEG];
#pragma unroll
        for (int a = 0; a < MAX_DEG; ++a) {
            f8[a] = *reinterpret_cast<const bf16x4*>(eo2 + (size_t)id[a] * 128 + lp * 4);
            nd[a] = f2[id[a]];
        }
        const float c = g2v[nid];
        float wgt[MAX_DEG];
        float smax = -1e30f;
#pragma unroll
        for (int a = 0; a < MAX_DEG; ++a) {
            float sc = val[a] ? lrelu(c + nd[a]) : -3e30f;
            wgt[a] = sc;
            if (val[a]) smax = fmaxf(smax, sc);
        }
        float denom = 0.f;
#pragma unroll
        for (int a = 0; a < MAX_DEG; ++a) {
            float ex = val[a] ? expf(wgt[a] - smax) : 0.f;
            wgt[a] = ex;
            denom += ex;
        }
        float inv = 1.f / denom;
        float acc[4] = {0.f, 0.f, 0.f, 0.f};
#pragma unroll
        for (int a = 0; a < MAX_DEG; ++a)
#pragma unroll
            for (int j = 0; j < 4; ++j) acc[j] = fmaf(wgt[a], (float)f8[a][j], acc[j]);
        v = make_float4(eluf(acc[0] * inv), eluf(acc[1] * inv), eluf(acc[2] * inv),
                        eluf(acc[3] * inv));
    } else {
        v = make_float4(1.f, 1.f, 1.f, 1.f);
    }
    *reinterpret_cast<float4*>(out + (size_t)b * 896 + s * 128 + lp * 4) = v;
}

// ---------------------------------------------------------------------------
extern "C" void kernel_launch(void* const* d_in, const int* in_sizes, int n_in,
                              void* d_out, int out_size, void* d_ws, size_t ws_size,
                              hipStream_t stream) {
    const int* batch_inputs = (const int*)d_in[0];
    const int* edge_list = (const int*)d_in[1];
    const int* node_list = (const int*)d_in[2];
    const float* node_embs = (const float*)d_in[3];
    const float* edge_embs = (const float*)d_in[4];
    const float* Wn = (const float*)d_in[5];
    const float* We = (const float*)d_in[6];
    const float* a1 = (const float*)d_in[7];
    const float* a2 = (const float*)d_in[8];
    const float* Wn_o = (const float*)d_in[9];
    const float* We_o = (const float*)d_in[10];
    const float* a1_o = (const float*)d_in[11];
    const float* a2_o = (const float*)d_in[12];
    float* out = (float*)d_out;
    char* ws = (char*)d_ws;

    // ---- workspace layout (bytes) ----
    __bf16* B1n = (__bf16*)(ws);                      // 65,536
    __bf16* B2n = (__bf16*)(ws + 65536);              // 65,536
    float* wc1 = (float*)(ws + 131072);               // 2,048
    float* wc2 = (float*)(ws + 133120);               // 1,024
    float* c1 = (float*)(ws + 134144);                // 400,000
    float* d1 = (float*)(ws + 534144);                // 800,000
    float* g1v = (float*)(ws + 1334144);              // 800,000
    float* f1 = (float*)(ws + 2134144);               // 400,000
    float* c2 = (float*)(ws + 2534144);               // 100,000
    float* d2 = (float*)(ws + 2634144);               // 200,000
    float* g2v = (float*)(ws + 2834144);              // 200,000
    float* f2 = (float*)(ws + 3034144);               // 100,000
    unsigned char* hn1 = (unsigned char*)(ws + 3134144);  // 12,800,000 (50000x256 fp8)
    __bf16* A2n = (__bf16*)(ws + 15934144);           // 25,624,576 (bf16 frags)
    __bf16* hn2 = (__bf16*)(ws + 41558720);           // 12,800,000 (50000x128 bf16)
    unsigned char* eo1 = (unsigned char*)(ws + 54358720); // 6,400,000 (25000x256 fp8)
    __bf16* eo2 = (__bf16*)(ws + 60758720);           // 6,400,000 -> ends 67,158,720

    // 1) merged prep (weight conversions + he-elimination dots)
    prep_kernel<<<PREP_TOTAL_BLKS, 256, 0, stream>>>(edge_embs, Wn, We, a1, Wn_o, We_o, a1_o,
                                                     B1n, B2n, wc1, wc2, c1);

    // 2) G1n: hn1(fp8) = node_embs(f32, direct) @ Wn  (+ d1, g1v)
    {
        dim3 g(4, MT_N / 8);
        mgemm1_kernel<<<g, 256, 0, stream>>>(node_embs, B1n, hn1, a1, a2, d1, g1v);
    }
    // 3) layer-1 edge attention -> eo1(fp8), f1, c2
    attn64e_kernel<<<(N_EDGES / 2 + 3) / 4, 256, 0, stream>>>(edge_list, hn1, c1, d1, a2, wc2,
                                                              eo1, f1, c2, N_EDGES);
    // 4) layer-1 node attention -> A2n (elu'd bf16 frags)  [standalone, high occ]
    attn64n_kernel<<<(MT_N * 16 / 2 + 3) / 4, 256, 0, stream>>>(node_list, eo1, g1v, f1, A2n,
                                                                N_NODES, MT_N * 16);
    // 5) G2n: hn2(bf16) = A2n @ Wn_o (+ d2, g2v)   [MPW=1 -> 782 blocks]
    {
        dim3 g(1, MT_N / 4);
        mgemm2_kernel<<<g, 256, 0, stream>>>(A2n, B2n, hn2, a1_o, a2_o, d2, g2v);
    }
    // 6) layer-2 edge attention -> eo2(bf16), f2
    attn128e_kernel<<<(N_EDGES / 4 + 3) / 4, 256, 0, stream>>>(edge_list, hn2, c2, d2, a2_o,
                                                               eo2, f2, N_EDGES);
    // 7) BATCH2: fused layer-2 node attention + batch gather (no no2 table)
    batch2_kernel<<<(BATCH * 7 / 2 + 3) / 4, 256, 0, stream>>>(batch_inputs, node_list, eo2,
                                                               g2v, f2, out);
}